// Round 6
// baseline (925.941 us; speedup 1.0000x reference)
//
#include <hip/hip_runtime.h>
#include <hip/hip_bf16.h>
#include <stdint.h>

// out[b,o] = sum_{k,i} hyp[b,k]*h[b,i]*W2[k,i*256+o] + sum_i h[b,i]*b2[i*256+o] + bias[o]
// GEMM A[4096 x 131328] * B[131328 x 256], A = diag(hyp_k)*H per k-group.
// A lives in registers (bf16 h pre-cast); partial products scaled by hyp in fp32:
// acc += sc_k * (H_tile . B_tile). hyp scales from a 32KB LDS slab.
// B = W2 flat bf16, pre-packed transposed+swizzled, streamed via global_load_lds into
// a 4-slot LDS ring; TWO tiles per iteration, one vmcnt(0)+s_barrier per iteration.
// Wave grid 1x8: each wave owns 128 rows x 32 cols -> every B byte read from LDS once.
// ws: [0,8.4M) hypT fp32 [513][4096] (row 512 = ones, folds b2); [9M,+2M) h bf16; [12M,+67.2M) packed B.

typedef __bf16 bf16x8 __attribute__((ext_vector_type(8)));
typedef float  f32x4  __attribute__((ext_vector_type(4)));

#define KTILES     2052
#define TILE_BYTES 32768          // 256 cols * 64 k * 2B
#define HB_OFF     (9u*1024u*1024u)
#define BP_OFF     (12u*1024u*1024u)

// ---------------- out = bias ----------------
__global__ void k_init_out(const float* __restrict__ bias, float* __restrict__ out) {
    int idx = blockIdx.x * 256 + threadIdx.x;
    out[idx] = bias[idx & 255];
}

// ---------------- h fp32 -> bf16 ----------------
__global__ void k_hcast(const float* __restrict__ h, uint16_t* __restrict__ hb) {
    int i = (blockIdx.x * 256 + threadIdx.x) * 8;    // grid 512 x 256
    f32x4 a = *(const f32x4*)(h + i);
    f32x4 b = *(const f32x4*)(h + i + 4);
    bf16x8 v;
    v[0] = (__bf16)a[0]; v[1] = (__bf16)a[1]; v[2] = (__bf16)a[2]; v[3] = (__bf16)a[3];
    v[4] = (__bf16)b[0]; v[5] = (__bf16)b[1]; v[6] = (__bf16)b[2]; v[7] = (__bf16)b[3];
    *(bf16x8*)(hb + i) = v;
}

// ---------------- hypT[k][b] = relu(z@W1+b1)^T; row 512 = 1.0 ----------------
__global__ void k_hypT(const float* __restrict__ z, const float* __restrict__ W1,
                       const float* __restrict__ b1, float* __restrict__ hypT) {
    int blk = blockIdx.x;
    int t   = threadIdx.x;                       // 512 threads; t == k
    if (blk == 128) {                            // ones row (b2 scale)
#pragma unroll
        for (int r = 0; r < 8; ++r) hypT[(size_t)512*4096 + r*512 + t] = 1.0f;
        return;
    }
    __shared__ float zs[32][128];
    int b0 = blk * 32;
#pragma unroll
    for (int u = 0; u < 8; ++u) {
        int idx = u * 512 + t;
        zs[idx >> 7][idx & 127] = z[b0 * 128 + idx];
    }
    __syncthreads();
    float acc[32];
    float bk = b1[t];
#pragma unroll
    for (int b = 0; b < 32; ++b) acc[b] = bk;
    for (int c = 0; c < 128; ++c) {
        float w = W1[c * 512 + t];
#pragma unroll
        for (int b = 0; b < 32; ++b) acc[b] = fmaf(zs[b][c], w, acc[b]);
    }
    float* dst = hypT + (size_t)t * 4096 + b0;
#pragma unroll
    for (int v = 0; v < 8; ++v) {
        f32x4 o;
#pragma unroll
        for (int q = 0; q < 4; ++q) {
            float a = acc[v * 4 + q];
            o[q] = a > 0.f ? a : 0.f;
        }
        *(f32x4*)(dst + v * 4) = o;
    }
}

// ---------------- pack W2 (+b2) -> bf16 transposed+swizzled tiles ----------------
// dst element (kk,o) at byte (o*128 + kk*2) ^ ((o&7)<<4); build in LDS, stream out 16B.
__global__ void k_pack(const float* __restrict__ W2, const float* __restrict__ b2,
                       uint16_t* __restrict__ Bp) {
    __shared__ char tile[TILE_BYTES];
    int t   = blockIdx.x;
    int tid = threadIdx.x;        // 256
    long row0 = (long)t * 64;
    const float* src = (t < 2048) ? (W2 + row0 * 256) : (b2 + (row0 - 131072) * 256);
#pragma unroll
    for (int u = 0; u < 16; ++u) {
        int f = (u * 256 + tid) * 4;              // flat fp32 idx, coalesced
        f32x4 v = *(const f32x4*)(src + f);
        int kk = f >> 8;
        int o0 = f & 255;
#pragma unroll
        for (int j = 0; j < 4; ++j) {
            int o = o0 + j;
            int addr = (o * 128 + kk * 2) ^ ((o & 7) << 4);
            *(__bf16*)(tile + addr) = (__bf16)v[j];
        }
    }
    __syncthreads();
    char* dst = (char*)Bp + (size_t)t * TILE_BYTES;
#pragma unroll
    for (int v = 0; v < 8; ++v) {
        int off = (v * 256 + tid) * 16;           // coalesced 16B copy out
        *(f32x4*)(dst + off) = *(const f32x4*)(tile + off);
    }
}

// ---------------- main GEMM: BM=128, BN=256, 8 waves (1x8), 4-ring, 2 tiles/iter ------
// grid 256 = 8 K-slabs (==XCD) x 32 mt; LDS = 4x32KB ring + 32KB hyp slab = 160KB.
__global__ __launch_bounds__(512, 1) void k_gemm(
        const uint16_t* __restrict__ hb, const float* __restrict__ hypT,
        const uint16_t* __restrict__ Bp, float* __restrict__ out) {
    __shared__ char smem[163840];

    const int tid  = threadIdx.x;
    const int lane = tid & 63;
    const int wid  = tid >> 6;                 // 8 waves; wave owns cols [wid*32, +32)
    const int l15  = lane & 15, lg = lane >> 4;

    const int bid = blockIdx.x;                // 256
    const int s   = bid & 7;                   // K-slab == XCD (round-robin dispatch)
    const int mt  = bid >> 3;                  // 0..31
    const int k0  = s * 64;
    const int row_base = mt * 128;
    const int NT  = (s == 7) ? 260 : 256;      // slab 7 owns the 4 b2 tiles
    const int colw = wid * 32;

    float* shyp = (float*)(smem + 131072);     // [64 kk][128 r] fp32

    // ---- prologue: hyp slab -> LDS (one-time) ----
#pragma unroll
    for (int u = 0; u < 4; ++u) {
        int f  = (u * 512 + tid) * 4;          // 8192 floats
        int kk = f >> 7;
        int r  = f & 127;
        *(f32x4*)(shyp + kk * 128 + r) =
            *(const f32x4*)(hypT + (size_t)(k0 + kk) * 4096 + row_base + r);
    }

    auto tile_of = [&](int idx) {
        return (idx < 256) ? ((k0 + (idx & 63)) * 4 + (idx >> 6)) : (2048 + idx - 256);
    };
    auto stage = [&](int slot, int t) {
        const char* gsrc = (const char*)Bp + (size_t)t * TILE_BYTES + wid * 4096 + lane * 16;
        char* ldst = smem + (slot << 15) + wid * 4096;   // wave-uniform base, lane*16 implicit
#pragma unroll
        for (int q = 0; q < 4; ++q)
            __builtin_amdgcn_global_load_lds(
                (const __attribute__((address_space(1))) void*)(gsrc + q * 1024),
                (__attribute__((address_space(3))) void*)(ldst + q * 1024), 16, 0, 0);
    };

    stage(0, tile_of(0));
    stage(1, tile_of(1));
    asm volatile("s_waitcnt vmcnt(0) lgkmcnt(0)" ::: "memory");  // tiles 0,1 + shyp ready
    __builtin_amdgcn_s_barrier();

    f32x4 acc[8][2];
#pragma unroll
    for (int i = 0; i < 8; ++i)
#pragma unroll
        for (int j = 0; j < 2; ++j)
#pragma unroll
            for (int q = 0; q < 4; ++q) acc[i][j][q] = 0.0f;

    const f32x4 fzero = {0.f, 0.f, 0.f, 0.f};

    for (int G = 0; G < 4; ++G) {
        // A-frags for this i0-group: 16 direct bf16 16B loads (all 128 rows)
        bf16x8 af[8][2];
#pragma unroll
        for (int mf = 0; mf < 8; ++mf)
#pragma unroll
            for (int ks = 0; ks < 2; ++ks)
                af[mf][ks] = *(const bf16x8*)(hb + (size_t)(row_base + mf * 16 + l15) * 256
                                              + G * 64 + ks * 32 + lg * 8);

        for (int jj = 0; jj < 32; ++jj) {
            const int idx0 = G * 64 + jj * 2;          // this iter: tiles idx0, idx0+1
            // prefetch next iteration's two tiles into the slots freed last iteration
            if (idx0 + 2 < NT) stage((idx0 + 2) & 3, tile_of(idx0 + 2));
            if (idx0 + 3 < NT) stage((idx0 + 3) & 3, tile_of(idx0 + 3));

            const char* sB0 = smem + ((idx0 & 3) << 15);
            const char* sB1 = smem + (((idx0 + 1) & 3) << 15);
            bf16x8 b00[2], b01[2], b10[2], b11[2];
#pragma unroll
            for (int nf = 0; nf < 2; ++nf) {
                int col = colw + nf * 16 + l15;
                int swz = (col & 7) << 4;
                int o0  = (col * 128 + lg * 16) ^ swz;
                int o1  = (col * 128 + 64 + lg * 16) ^ swz;
                b00[nf] = *(const bf16x8*)(sB0 + o0);
                b01[nf] = *(const bf16x8*)(sB0 + o1);
                b10[nf] = *(const bf16x8*)(sB1 + o0);
                b11[nf] = *(const bf16x8*)(sB1 + o1);
            }
            f32x4 scv0[8], scv1[8];
#pragma unroll
            for (int mf = 0; mf < 8; ++mf) {
                scv0[mf] = *(const f32x4*)(shyp + (jj * 2) * 128 + mf * 16 + lg * 4);
                scv1[mf] = *(const f32x4*)(shyp + (jj * 2 + 1) * 128 + mf * 16 + lg * 4);
            }

            __builtin_amdgcn_s_setprio(1);
#pragma unroll
            for (int mf = 0; mf < 8; ++mf)
#pragma unroll
                for (int nf = 0; nf < 2; ++nf) {
                    f32x4 p = __builtin_amdgcn_mfma_f32_16x16x32_bf16(af[mf][0], b00[nf], fzero, 0, 0, 0);
                    p = __builtin_amdgcn_mfma_f32_16x16x32_bf16(af[mf][1], b01[nf], p, 0, 0, 0);
#pragma unroll
                    for (int q = 0; q < 4; ++q)
                        acc[mf][nf][q] = fmaf(scv0[mf][q], p[q], acc[mf][nf][q]);
                }
#pragma unroll
            for (int mf = 0; mf < 8; ++mf)
#pragma unroll
                for (int nf = 0; nf < 2; ++nf) {
                    f32x4 p = __builtin_amdgcn_mfma_f32_16x16x32_bf16(af[mf][0], b10[nf], fzero, 0, 0, 0);
                    p = __builtin_amdgcn_mfma_f32_16x16x32_bf16(af[mf][1], b11[nf], p, 0, 0, 0);
#pragma unroll
                    for (int q = 0; q < 4; ++q)
                        acc[mf][nf][q] = fmaf(scv1[mf][q], p[q], acc[mf][nf][q]);
                }
            __builtin_amdgcn_s_setprio(0);

            // next iter's tiles were issued ~1 full iteration ago -> near-zero wait
            asm volatile("s_waitcnt vmcnt(0)" ::: "memory");
            __builtin_amdgcn_s_barrier();
        }
    }

    // ---- b2 tail (slab 7 only): tiles 2048..2051, scale 1, one tile per step ----
    if (s == 7) {
        for (int g = 0; g < 4; ++g) {
            int idx = 256 + g;
            if (idx + 2 < 260) stage((idx + 2) & 3, tile_of(idx + 2));
            bf16x8 af[8][2];
#pragma unroll
            for (int mf = 0; mf < 8; ++mf)
#pragma unroll
                for (int ks = 0; ks < 2; ++ks)
                    af[mf][ks] = *(const bf16x8*)(hb + (size_t)(row_base + mf * 16 + l15) * 256
                                                  + g * 64 + ks * 32 + lg * 8);
            const char* sB = smem + ((idx & 3) << 15);
#pragma unroll
            for (int nf = 0; nf < 2; ++nf) {
                int col = colw + nf * 16 + l15;
                int swz = (col & 7) << 4;
                bf16x8 u0 = *(const bf16x8*)(sB + ((col * 128 + lg * 16) ^ swz));
                bf16x8 u1 = *(const bf16x8*)(sB + ((col * 128 + 64 + lg * 16) ^ swz));
#pragma unroll
                for (int mf = 0; mf < 8; ++mf) {
                    f32x4 p = __builtin_amdgcn_mfma_f32_16x16x32_bf16(af[mf][0], u0, fzero, 0, 0, 0);
                    p = __builtin_amdgcn_mfma_f32_16x16x32_bf16(af[mf][1], u1, p, 0, 0, 0);
#pragma unroll
                    for (int q = 0; q < 4; ++q) acc[mf][nf][q] += p[q];
                }
            }
            asm volatile("s_waitcnt vmcnt(0)" ::: "memory");
            __builtin_amdgcn_s_barrier();
        }
    }

    // ---- epilogue: atomic split-K accumulate (out pre-initialized with bias) ----
#pragma unroll
    for (int mf = 0; mf < 8; ++mf)
#pragma unroll
        for (int nf = 0; nf < 2; ++nf) {
            int col = colw + nf * 16 + l15;
#pragma unroll
            for (int q = 0; q < 4; ++q) {
                int row = row_base + mf * 16 + lg * 4 + q;  // C/D: col=lane&15, row=(lane>>4)*4+q
                atomicAdd(&out[row * 256 + col], acc[mf][nf][q]);
            }
        }
}

extern "C" void kernel_launch(void* const* d_in, const int* in_sizes, int n_in,
                              void* d_out, int out_size, void* d_ws, size_t ws_size,
                              hipStream_t stream) {
    const float* h    = (const float*)d_in[0];  // [4096,256]
    const float* z    = (const float*)d_in[1];  // [4096,128]
    const float* W1   = (const float*)d_in[2];  // [128,512]
    const float* b1   = (const float*)d_in[3];  // [512]
    const float* W2   = (const float*)d_in[4];  // [512,65536]
    const float* b2   = (const float*)d_in[5];  // [65536]
    const float* bias = (const float*)d_in[6];  // [1,256]
    float* out = (float*)d_out;                 // [4096,256] fp32

    float*    hypT = (float*)d_ws;                          // 513*4096*4 = 8.4 MB
    uint16_t* hb   = (uint16_t*)((char*)d_ws + HB_OFF);     // 2 MB bf16 h
    uint16_t* Bp   = (uint16_t*)((char*)d_ws + BP_OFF);     // 67.2 MB

    k_pack    <<<KTILES, 256, 0, stream>>>(W2, b2, Bp);
    k_hypT    <<<129,    512, 0, stream>>>(z, W1, b1, hypT);
    k_hcast   <<<512,    256, 0, stream>>>(h, hb);
    k_init_out<<<4096,   256, 0, stream>>>(bias, out);
    k_gemm    <<<256,    512, 0, stream>>>(hb, hypT, Bp, out);
}

// Round 7
// 328.204 us; speedup vs baseline: 2.8212x; 2.8212x over previous
//
#include <hip/hip_runtime.h>
#include <hip/hip_bf16.h>
#include <stdint.h>

// out[b,o] = sum_{k,i} hyp[b,k]*h[b,i]*W2[k,i*256+o] + sum_i h[b,i]*b2[i*256+o] + bias[o]
// GEMM A[4096 x 131328] * B[131328 x 256], A = diag(hyp_k)*H per k-group — all in FP16.
// A-frag built in regs: as = sc_row * h_frag via v_pk_mul_f16 (A-row is lane-local, l15),
// MFMA accumulates directly into acc (C operand) — no fp32 scale-accumulate pass.
// B = W2 flat f16, pre-packed transposed+swizzled, streamed via global_load_lds into a
// 3-deep LDS ring, counted vmcnt(4), ONE raw s_barrier per iteration, setprio on MFMA.
// ws: [0,8.4M) hypT fp32 [513][4096] (row 512 = ones, folds b2); [9M,+2M) h f16; [12M,+67.2M) packed B.

typedef _Float16 f16x8 __attribute__((ext_vector_type(8)));
typedef float    f32x4 __attribute__((ext_vector_type(4)));

#define KTILES     2052
#define TILE_BYTES 32768          // 256 cols * 64 k * 2B
#define HB_OFF     (9u*1024u*1024u)
#define BP_OFF     (12u*1024u*1024u)

// ---------------- out = bias ----------------
__global__ void k_init_out(const float* __restrict__ bias, float* __restrict__ out) {
    int idx = blockIdx.x * 256 + threadIdx.x;
    out[idx] = bias[idx & 255];
}

// ---------------- h fp32 -> f16 ----------------
__global__ void k_hcast(const float* __restrict__ h, _Float16* __restrict__ hb) {
    int i = (blockIdx.x * 256 + threadIdx.x) * 8;    // grid 512 x 256
    f32x4 a = *(const f32x4*)(h + i);
    f32x4 b = *(const f32x4*)(h + i + 4);
    f16x8 v;
    v[0] = (_Float16)a[0]; v[1] = (_Float16)a[1]; v[2] = (_Float16)a[2]; v[3] = (_Float16)a[3];
    v[4] = (_Float16)b[0]; v[5] = (_Float16)b[1]; v[6] = (_Float16)b[2]; v[7] = (_Float16)b[3];
    *(f16x8*)(hb + i) = v;
}

// ---------------- hypT[k][b] = relu(z@W1+b1)^T; row 512 = 1.0 ----------------
__global__ void k_hypT(const float* __restrict__ z, const float* __restrict__ W1,
                       const float* __restrict__ b1, float* __restrict__ hypT) {
    int blk = blockIdx.x;
    int t   = threadIdx.x;                       // 512 threads; t == k
    if (blk == 128) {                            // ones row (b2 scale)
#pragma unroll
        for (int r = 0; r < 8; ++r) hypT[(size_t)512*4096 + r*512 + t] = 1.0f;
        return;
    }
    __shared__ float zs[32][128];
    int b0 = blk * 32;
#pragma unroll
    for (int u = 0; u < 8; ++u) {
        int idx = u * 512 + t;
        zs[idx >> 7][idx & 127] = z[b0 * 128 + idx];
    }
    __syncthreads();
    float acc[32];
    float bk = b1[t];
#pragma unroll
    for (int b = 0; b < 32; ++b) acc[b] = bk;
    for (int c = 0; c < 128; ++c) {
        float w = W1[c * 512 + t];
#pragma unroll
        for (int b = 0; b < 32; ++b) acc[b] = fmaf(zs[b][c], w, acc[b]);
    }
    float* dst = hypT + (size_t)t * 4096 + b0;
#pragma unroll
    for (int v = 0; v < 8; ++v) {
        f32x4 o;
#pragma unroll
        for (int q = 0; q < 4; ++q) {
            float a = acc[v * 4 + q];
            o[q] = a > 0.f ? a : 0.f;
        }
        *(f32x4*)(dst + v * 4) = o;
    }
}

// ---------------- pack W2 (+b2) -> f16 transposed+swizzled tiles ----------------
// dst element (kk,o) at byte (o*128 + kk*2) ^ ((o&7)<<4); build in LDS, stream out 16B.
__global__ void k_pack(const float* __restrict__ W2, const float* __restrict__ b2,
                       _Float16* __restrict__ Bp) {
    __shared__ char tile[TILE_BYTES];
    int t   = blockIdx.x;
    int tid = threadIdx.x;        // 256
    long row0 = (long)t * 64;
    const float* src = (t < 2048) ? (W2 + row0 * 256) : (b2 + (row0 - 131072) * 256);
#pragma unroll
    for (int u = 0; u < 16; ++u) {
        int f = (u * 256 + tid) * 4;              // flat fp32 idx, coalesced
        f32x4 v = *(const f32x4*)(src + f);
        int kk = f >> 8;
        int o0 = f & 255;
#pragma unroll
        for (int j = 0; j < 4; ++j) {
            int o = o0 + j;
            int addr = (o * 128 + kk * 2) ^ ((o & 7) << 4);
            *(_Float16*)(tile + addr) = (_Float16)v[j];
        }
    }
    __syncthreads();
    char* dst = (char*)Bp + (size_t)t * TILE_BYTES;
#pragma unroll
    for (int v = 0; v < 8; ++v) {
        int off = (v * 256 + tid) * 16;           // coalesced 16B copy out
        *(f32x4*)(dst + off) = *(const f32x4*)(tile + off);
    }
}

// ---------------- main GEMM: BM=128, BN=256, 8 waves (2x4), 3-deep ring ----------------
// grid 256 = 8 K-slabs (==XCD) x 32 mt; LDS = 3x32KB B ring + 32KB hyp slab = 128KB.
__global__ __launch_bounds__(512, 2) void k_gemm(
        const _Float16* __restrict__ hb, const float* __restrict__ hypT,
        const _Float16* __restrict__ Bp, float* __restrict__ out) {
    __shared__ char smem[131072];

    const int tid  = threadIdx.x;
    const int lane = tid & 63;
    const int wid  = tid >> 6;                 // 8 waves
    const int wm   = wid >> 2, wn = wid & 3;   // 2 x 4 wave grid, 64x64 out each
    const int l15  = lane & 15, lg = lane >> 4;

    const int bid = blockIdx.x;                // 256
    const int s   = bid & 7;                   // K-slab == XCD
    const int mt  = bid >> 3;                  // 0..31
    const int k0  = s * 64;
    const int row_base = mt * 128;
    const int NT  = (s == 7) ? 260 : 256;      // slab 7 owns the 4 b2 tiles

    float* shyp = (float*)(smem + 98304);      // [64 kk][128 r] fp32

    // ---- prologue: hyp slab -> LDS (one-time) ----
#pragma unroll
    for (int u = 0; u < 4; ++u) {
        int f  = (u * 512 + tid) * 4;          // 8192 floats
        int kk = f >> 7;
        int r  = f & 127;
        *(f32x4*)(shyp + kk * 128 + r) =
            *(const f32x4*)(hypT + (size_t)(k0 + kk) * 4096 + row_base + r);
    }

    auto tile_of = [&](int idx) {
        return (idx < 256) ? ((k0 + (idx & 63)) * 4 + (idx >> 6)) : (2048 + idx - 256);
    };
    auto stage = [&](int bufoff, int t) {
        const char* gsrc = (const char*)Bp + (size_t)t * TILE_BYTES + wid * 4096 + lane * 16;
        char* ldst = smem + bufoff + wid * 4096;    // wave-uniform base, lane*16 implicit
#pragma unroll
        for (int q = 0; q < 4; ++q)
            __builtin_amdgcn_global_load_lds(
                (const __attribute__((address_space(1))) void*)(gsrc + q * 1024),
                (__attribute__((address_space(3))) void*)(ldst + q * 1024), 16, 0, 0);
    };

    stage(0,     tile_of(0));
    stage(32768, tile_of(1));
    asm volatile("s_waitcnt vmcnt(4) lgkmcnt(0)" ::: "memory");  // tile0 + shyp done
    __builtin_amdgcn_s_barrier();

    f32x4 acc[4][4];
#pragma unroll
    for (int i = 0; i < 4; ++i)
#pragma unroll
        for (int j = 0; j < 4; ++j)
#pragma unroll
            for (int q = 0; q < 4; ++q) acc[i][j][q] = 0.0f;

    int boff_read = 0, boff_next = 32768, boff_stage = 65536;

    for (int G = 0; G < 8; ++G) {              // 0..3 main (64 iters), 4..7 b2 tail (s==7)
        if (G >= 4 && s != 7) break;
        const int niter = (G < 4) ? 64 : 1;

        // A-frags for this i0-group: 8 direct f16 16B loads (wave's 64 rows)
        f16x8 af[4][2];
#pragma unroll
        for (int mf = 0; mf < 4; ++mf)
#pragma unroll
            for (int ks = 0; ks < 2; ++ks)
                af[mf][ks] = *(const f16x8*)(hb + (size_t)(row_base + wm * 64 + mf * 16 + l15) * 256
                                             + (G & 3) * 64 + ks * 32 + lg * 8);

        for (int jj = 0; jj < niter; ++jj) {
            const int idx = (G < 4) ? G * 64 + jj : 256 + (G - 4);
            const bool do_stage = (idx + 2 < NT);
            if (do_stage) stage(boff_stage, tile_of(idx + 2));   // prefetch depth-2

            // B-frags from current ring buffer (swizzled ds_read_b128)
            const char* sB = smem + boff_read;
            f16x8 b0[4], b1[4];
#pragma unroll
            for (int nf = 0; nf < 4; ++nf) {
                int col = wn * 64 + nf * 16 + l15;
                int swz = (col & 7) << 4;
                b0[nf] = *(const f16x8*)(sB + ((col * 128 + lg * 16) ^ swz));
                b1[nf] = *(const f16x8*)(sB + ((col * 128 + 64 + lg * 16) ^ swz));
            }
            // per-lane A-row scale (broadcast ds_read_b32, conflict-free)
            _Float16 sch[4];
            if (idx < 256) {
#pragma unroll
                for (int mf = 0; mf < 4; ++mf)
                    sch[mf] = (_Float16)shyp[jj * 128 + wm * 64 + mf * 16 + l15];
            } else {
#pragma unroll
                for (int mf = 0; mf < 4; ++mf) sch[mf] = (_Float16)1.0f;
            }

            __builtin_amdgcn_s_setprio(1);
#pragma unroll
            for (int mf = 0; mf < 4; ++mf) {
                f16x8 as0 = af[mf][0] * sch[mf];   // v_pk_mul_f16 x4
                f16x8 as1 = af[mf][1] * sch[mf];
#pragma unroll
                for (int nf = 0; nf < 4; ++nf)
                    acc[mf][nf] = __builtin_amdgcn_mfma_f32_16x16x32_f16(as0, b0[nf], acc[mf][nf], 0, 0, 0);
#pragma unroll
                for (int nf = 0; nf < 4; ++nf)
                    acc[mf][nf] = __builtin_amdgcn_mfma_f32_16x16x32_f16(as1, b1[nf], acc[mf][nf], 0, 0, 0);
            }
            __builtin_amdgcn_s_setprio(0);

            // counted wait: idx+1's loads landed, idx+2's stay in flight
            if (do_stage) asm volatile("s_waitcnt vmcnt(4)" ::: "memory");
            else          asm volatile("s_waitcnt vmcnt(0)" ::: "memory");
            __builtin_amdgcn_s_barrier();

            int tmp = boff_read; boff_read = boff_next; boff_next = boff_stage; boff_stage = tmp;
        }
    }

    // ---- epilogue: atomic split-K accumulate (out pre-initialized with bias) ----
    int crow0 = row_base + wm * 64;
    int ccol0 = wn * 64;
#pragma unroll
    for (int mf = 0; mf < 4; ++mf)
#pragma unroll
        for (int nf = 0; nf < 4; ++nf) {
            int col = ccol0 + nf * 16 + l15;
#pragma unroll
            for (int q = 0; q < 4; ++q) {
                int row = crow0 + mf * 16 + lg * 4 + q;   // C/D: col=lane&15, row=(lane>>4)*4+q
                atomicAdd(&out[row * 256 + col], acc[mf][nf][q]);
            }
        }
}

extern "C" void kernel_launch(void* const* d_in, const int* in_sizes, int n_in,
                              void* d_out, int out_size, void* d_ws, size_t ws_size,
                              hipStream_t stream) {
    const float* h    = (const float*)d_in[0];  // [4096,256]
    const float* z    = (const float*)d_in[1];  // [4096,128]
    const float* W1   = (const float*)d_in[2];  // [128,512]
    const float* b1   = (const float*)d_in[3];  // [512]
    const float* W2   = (const float*)d_in[4];  // [512,65536]
    const float* b2   = (const float*)d_in[5];  // [65536]
    const float* bias = (const float*)d_in[6];  // [1,256]
    float* out = (float*)d_out;                 // [4096,256] fp32

    float*     hypT = (float*)d_ws;                          // 513*4096*4 = 8.4 MB
    _Float16*  hb   = (_Float16*)((char*)d_ws + HB_OFF);     // 2 MB f16 h
    _Float16*  Bp   = (_Float16*)((char*)d_ws + BP_OFF);     // 67.2 MB

    k_pack    <<<KTILES, 256, 0, stream>>>(W2, b2, Bp);
    k_hypT    <<<129,    512, 0, stream>>>(z, W1, b1, hypT);
    k_hcast   <<<512,    256, 0, stream>>>(h, hb);
    k_init_out<<<4096,   256, 0, stream>>>(bias, out);
    k_gemm    <<<256,    512, 0, stream>>>(hb, hypT, Bp, out);
}